// Round 2
// baseline (346.592 us; speedup 1.0000x reference)
//
#include <hip/hip_runtime.h>

// VQ quantizer, fp32: z [131072,64], e [2048,64].
// d_out (flat f32): z_q [131072*64] | indices [131072] (floats) | loss [1].
//
// 2-split bf16 MFMA scan (hh, hl, lh products), argmax of s = dot - esq/2,
// acc initialized to -esq/2.
//
// R9: latency/occupancy attack. Counters showed 2 waves/SIMD (grid-limited)
// with ~60% stall cycles (MfmaUtil 27.7, VALU-only ~11, HBM 5%). Changes:
//  - 32 rows/wave (RF=2), 1024 blocks, __launch_bounds__(256,4)
//    -> 4 waves/SIMD, VGPR ~110 (A-frags and argmax state halved).
//  - per-rf 6-deep dependent MFMA chain split into two 3-chains
//    (acc=en-init hh/hl/lh even half, acc2=0-init odd half, add at end).
// A-fragments PINNED via one-time empty asm ("+v") after the build:
// an asm def cannot be rematerialized -> no z-reload/f2bf redo in-loop.
// B tiles: register double-buffer, hand-unrolled x2, NO pins (counted vmcnt).
//
// Top-2 gap < EPS_S flags rows into a global list; exact f64 re-solve
// (LDS-staged z row, coalesced eT, f64 esq). T=0 => z_out = z_q = e[best].

#define N_ROWS 131072
#define ZD 64
#define KCODES 2048
#define RF 2                 // 16-row fragments per wave (32 rows/wave)
#define EPS_S 2e-3f          // s-scale gap; realistic split error ~2e-5
#define FLAG_CAP 32768

using bf16x8  = __attribute__((ext_vector_type(8))) short;
using floatx4 = __attribute__((ext_vector_type(4))) float;

__device__ inline float bf2f(unsigned short u) {
    union { unsigned int i; float f; } c; c.i = ((unsigned int)u) << 16; return c.f;
}
__device__ inline unsigned short f2bf(float x) {
    union { float f; unsigned int i; } c; c.f = x;
    unsigned int b = c.i + 0x7FFFu + ((c.i >> 16) & 1u);
    return (unsigned short)(b >> 16);
}

// ws byte layout:
//       0: loss f32 | 4: flag count u32
//    4096: esn f32[2048]   (= -esq/2, summed in f64)
//   16384: esq64 f64[2048]
//   32768: ehi u16[2048*64] | 294912: elo u16[2048*64]
//  557056: eT f32[64*2048]
// 1081344: flags u32[32768]   (ends 1212416)

__global__ void prep_kernel(const float* __restrict__ e, float* __restrict__ ws) {
    int t = threadIdx.x, lane = t & 63, w = t >> 6;
    if (blockIdx.x == 0 && t == 0) { ws[0] = 0.0f; ((unsigned int*)ws)[1] = 0u; }
    int c = blockIdx.x * 4 + w;                   // 512 blocks x 4 waves = 2048
    float* esn = ws + 1024;
    double* esq64 = (double*)((char*)ws + 16384);
    unsigned short* ehi = (unsigned short*)((char*)ws + 32768);
    unsigned short* elo = (unsigned short*)((char*)ws + 294912);
    float* eT = (float*)((char*)ws + 557056);

    float x = e[(size_t)c * ZD + lane];           // lane = dim k, coalesced
    unsigned short h = f2bf(x);
    ehi[c * ZD + lane] = h;
    elo[c * ZD + lane] = f2bf(x - bf2f(h));
    eT[lane * KCODES + c] = x;
    double s = (double)x * (double)x;
    for (int off = 1; off < 64; off <<= 1) s += __shfl_xor(s, off, 64);
    if (lane == 0) { esq64[c] = s; esn[c] = (float)(-0.5 * s); }
}

// Load one 16-code B tile (hi, lo, esn) into the given registers.
#define LOADB(H0, H1, L0, L1, EN, TT) do {                                   \
    int _n    = (TT) & 127;                                                  \
    int _noff = _n * 16 * ZD;                                                \
    H0 = *(const bf16x8*)(const void*)(bh + _noff);                          \
    H1 = *(const bf16x8*)(const void*)(bh + _noff + 32);                     \
    L0 = *(const bf16x8*)(const void*)(bl + _noff);                          \
    L1 = *(const bf16x8*)(const void*)(bl + _noff + 32);                     \
    EN = esn[_n * 16 + lrow];                                                \
} while (0)

// 12 MFMAs + argmax update for one 16-code tile.
// Two independent 3-chains per rf (acc: en-init, acc2: 0-init), summed.
// Top-2 invariant mval >= mv2: new mv2 = median(s, mval_old, mv2).
#define COMPUTE(H0, H1, L0, L1, EN, TT) do {                                 \
    float _fcol = (float)((TT) * 16 + lrow);                                 \
    floatx4 _ai = {EN, EN, EN, EN};                                          \
    floatx4 _zi = {0.0f, 0.0f, 0.0f, 0.0f};                                  \
    _Pragma("unroll")                                                        \
    for (int _rf = 0; _rf < RF; _rf++) {                                     \
        floatx4 acc  = _ai;                                                  \
        floatx4 acc2 = _zi;                                                  \
        acc  = __builtin_amdgcn_mfma_f32_16x16x32_bf16(Ah[_rf][0], H0, acc,  0, 0, 0); \
        acc2 = __builtin_amdgcn_mfma_f32_16x16x32_bf16(Ah[_rf][1], H1, acc2, 0, 0, 0); \
        acc  = __builtin_amdgcn_mfma_f32_16x16x32_bf16(Ah[_rf][0], L0, acc,  0, 0, 0); \
        acc2 = __builtin_amdgcn_mfma_f32_16x16x32_bf16(Ah[_rf][1], L1, acc2, 0, 0, 0); \
        acc  = __builtin_amdgcn_mfma_f32_16x16x32_bf16(Al[_rf][0], H0, acc,  0, 0, 0); \
        acc2 = __builtin_amdgcn_mfma_f32_16x16x32_bf16(Al[_rf][1], H1, acc2, 0, 0, 0); \
        _Pragma("unroll")                                                    \
        for (int _r = 0; _r < 4; _r++) {                                     \
            float _s  = acc[_r] + acc2[_r];                                  \
            bool  _gt = _s > mval[_rf][_r];                                  \
            mv2[_rf][_r]  = __builtin_amdgcn_fmed3f(_s, mval[_rf][_r], mv2[_rf][_r]); \
            midx[_rf][_r] = _gt ? _fcol : midx[_rf][_r];                     \
            mval[_rf][_r] = fmaxf(_s, mval[_rf][_r]);                        \
        }                                                                    \
    }                                                                        \
} while (0)

__global__ __launch_bounds__(256, 4) void vq_mfma(
        const float* __restrict__ z, const float* __restrict__ e,
        float* __restrict__ ws, float* __restrict__ out) {
    const float* esn = ws + 1024;
    const unsigned short* ehi = (const unsigned short*)((const char*)ws + 32768);
    const unsigned short* elo = (const unsigned short*)((const char*)ws + 294912);
    unsigned int* cntp  = (unsigned int*)ws + 1;
    unsigned int* flags = (unsigned int*)((char*)ws + 1081344);

    int lane = threadIdx.x & 63;
    int w    = threadIdx.x >> 6;
    int wid  = blockIdx.x * 4 + w;                // 0..4095
    int row0 = wid * (RF * 16);                   // 32 rows per wave
    int lrow = lane & 15;
    int lq   = lane >> 4;

    // Resident A fragments (hi+lo), A[m=lane&15][k=lq*8+j], kc = k-half
    bf16x8 Ah[RF][2], Al[RF][2];
#pragma unroll
    for (int rf = 0; rf < RF; rf++)
#pragma unroll
        for (int kc = 0; kc < 2; kc++) {
            const float* zp = z + (size_t)(row0 + rf * 16 + lrow) * ZD + kc * 32 + lq * 8;
            float xv[8];
            *(float4*)(void*)&xv[0] = *(const float4*)(const void*)zp;
            *(float4*)(void*)&xv[4] = *(const float4*)(const void*)(zp + 4);
            bf16x8 h, l;
#pragma unroll
            for (int j = 0; j < 8; j++) {
                unsigned short hb = f2bf(xv[j]);
                h[j] = (short)hb;
                l[j] = (short)f2bf(xv[j] - bf2f(hb));
            }
            Ah[rf][kc] = h; Al[rf][kc] = l;
            // Pin (ONE-TIME, outside loop): asm defs cannot be rematerialized
            // -> fragments stay register-resident across the 128-iter loop.
            asm volatile("" : "+v"(Ah[rf][kc]), "+v"(Al[rf][kc]));
        }

    // argmax state on s = dot - esq/2  (argmin d2 == argmax s)
    floatx4 mval[RF], mv2[RF], midx[RF];
#pragma unroll
    for (int rf = 0; rf < RF; rf++)
#pragma unroll
        for (int r = 0; r < 4; r++) {
            mval[rf][r] = -3.0e38f; mv2[rf][r] = -3.0e38f; midx[rf][r] = 0.0f;
        }

    const unsigned short* bh = ehi + lrow * ZD + lq * 8;
    const unsigned short* bl = elo + lrow * ZD + lq * 8;

    // Double-buffered register prefetch, hand-unrolled x2. NO pins on B:
    // loads for tile t+1 stay in flight (counted vmcnt) under tile t's MFMAs.
    bf16x8 ch0, ch1, cl0, cl1; float cen;
    bf16x8 nh0, nh1, nl0, nl1; float nen;
    LOADB(ch0, ch1, cl0, cl1, cen, 0);
    for (int ct = 0; ct < 128; ct += 2) {
        LOADB(nh0, nh1, nl0, nl1, nen, ct + 1);
        COMPUTE(ch0, ch1, cl0, cl1, cen, ct);
        LOADB(ch0, ch1, cl0, cl1, cen, ct + 2);   // wraps to 0 on last iter
        COMPUTE(nh0, nh1, nl0, nl1, nen, ct + 1);
    }

    float lacc = 0.0f;
#pragma unroll
    for (int rf = 0; rf < RF; rf++)
#pragma unroll
        for (int r = 0; r < 4; r++) {
            float v = mval[rf][r], v2 = mv2[rf][r], fi = midx[rf][r];
            // top-2 max-merge across the 16 lanes of this row (ties: smaller col)
            for (int off = 1; off < 16; off <<= 1) {
                float ov  = __shfl_xor(v,  off, 64);
                float ofi = __shfl_xor(fi, off, 64);
                float ov2 = __shfl_xor(v2, off, 64);
                bool take = (ov > v) || ((ov == v) && (ofi < fi));
                float loser = take ? v : ov;
                v2 = fmaxf(fmaxf(v2, ov2), loser);
                v  = take ? ov  : v;
                fi = take ? ofi : fi;
            }
            int row = row0 + rf * 16 + lq * 4 + r;
            int idx = (int)fi;
            float4 ev = ((const float4*)(const void*)(e + (size_t)idx * ZD))[lrow];
            float4 zv = ((const float4*)(const void*)(z + (size_t)row * ZD))[lrow];
            ((float4*)(void*)(out + (size_t)row * ZD))[lrow] = ev;
            float dx = ev.x - zv.x, dy = ev.y - zv.y;
            float dz = ev.z - zv.z, dw = ev.w - zv.w;
            lacc = fmaf(dx, dx, lacc); lacc = fmaf(dy, dy, lacc);
            lacc = fmaf(dz, dz, lacc); lacc = fmaf(dw, dw, lacc);
            if (lrow == 0) {
                out[(size_t)N_ROWS * ZD + row] = fi;
                if (v - v2 < EPS_S) {
                    unsigned int i = atomicAdd(cntp, 1u);
                    if (i < FLAG_CAP) flags[i] = (unsigned int)row;
                }
            }
        }

    for (int off = 1; off < 64; off <<= 1) lacc += __shfl_xor(lacc, off, 64);
    __shared__ float sm[4];
    if (lane == 0) sm[w] = lacc;
    __syncthreads();
    if (threadIdx.x == 0) atomicAdd(ws, sm[0] + sm[1] + sm[2] + sm[3]);
}

__global__ __launch_bounds__(256) void vq_fixup(
        const float* __restrict__ z, const float* __restrict__ e,
        float* __restrict__ ws, float* __restrict__ out) {
    const double* esq64 = (const double*)((const char*)ws + 16384);
    const float* eT = (const float*)((const char*)ws + 557056);
    const unsigned int* flags = (const unsigned int*)((const char*)ws + 1081344);
    unsigned int cnt = ((const unsigned int*)ws)[1];
    if (cnt > FLAG_CAP) cnt = FLAG_CAP;

    __shared__ float zrow[ZD];
    __shared__ double sd[4]; __shared__ int si[4]; __shared__ int sbest;
    int t = threadIdx.x, lane = t & 63, w = t >> 6;

    for (unsigned int u = blockIdx.x; u < cnt; u += gridDim.x) {
        int row = (int)flags[u];
        __syncthreads();                          // protect zrow from prev iter
        if (t < ZD) zrow[t] = z[(size_t)row * ZD + t];
        __syncthreads();

        double dacc[8];
#pragma unroll
        for (int j = 0; j < 8; j++) dacc[j] = 0.0;
        for (int k = 0; k < ZD; k++) {
            double zk = (double)zrow[k];
            const float* ek = eT + k * KCODES + t;
#pragma unroll
            for (int j = 0; j < 8; j++)
                dacc[j] = fma(zk, (double)ek[256 * j], dacc[j]);
        }
        double dmin = 1.0e300; int imin = 0;
#pragma unroll
        for (int j = 0; j < 8; j++) {             // ascending c: first wins
            int c = t + 256 * j;
            double d = fma(-2.0, dacc[j], esq64[c]);
            if (d < dmin) { dmin = d; imin = c; }
        }
        for (int off = 1; off < 64; off <<= 1) {
            double od = __shfl_xor(dmin, off, 64);
            int    oi = __shfl_xor(imin, off, 64);
            if (od < dmin || (od == dmin && oi < imin)) { dmin = od; imin = oi; }
        }
        if (lane == 0) { sd[w] = dmin; si[w] = imin; }
        __syncthreads();
        if (t == 0) {
            double bd = sd[0]; int bi = si[0];
            for (int q = 1; q < 4; q++)
                if (sd[q] < bd || (sd[q] == bd && si[q] < bi)) { bd = sd[q]; bi = si[q]; }
            sbest = bi;
        }
        __syncthreads();
        int bi = sbest;
        if (t < 16)
            ((float4*)(void*)(out + (size_t)row * ZD))[t] =
                ((const float4*)(const void*)(e + (size_t)bi * ZD))[t];
        if (t == 0) out[(size_t)N_ROWS * ZD + row] = (float)bi;
        // loss correction from flips: < EPS * ~700 / 8.4M < 2e-7 — ignored.
    }
}

__global__ void finalize_kernel(const float* __restrict__ ws,
                                float* __restrict__ out) {
    out[(size_t)N_ROWS * ZD + N_ROWS] = ws[0] * (1.0f / 8388608.0f);
}

extern "C" void kernel_launch(void* const* d_in, const int* in_sizes, int n_in,
                              void* d_out, int out_size, void* d_ws, size_t ws_size,
                              hipStream_t stream) {
    const float* z = (const float*)d_in[0];
    const float* e = (const float*)d_in[1];
    float* out = (float*)d_out;
    float* ws  = (float*)d_ws;

    prep_kernel<<<dim3(512), dim3(256), 0, stream>>>(e, ws);
    vq_mfma<<<dim3(1024), dim3(256), 0, stream>>>(z, e, ws, out);
    vq_fixup<<<dim3(256), dim3(256), 0, stream>>>(z, e, ws, out);
    finalize_kernel<<<dim3(1), dim3(1), 0, stream>>>(ws, out);
}

// Round 3
// 198.236 us; speedup vs baseline: 1.7484x; 1.7484x over previous
//
#include <hip/hip_runtime.h>

// VQ quantizer, fp32: z [131072,64], e [2048,64].
// d_out (flat f32): z_q [131072*64] | indices [131072] (floats) | loss [1].
//
// 2-split bf16 MFMA scan (hh, hl, lh products), argmax of s = dot - esq/2.
//
// R10: LDS-staged B tiles. R9 proved the B-load path is the bottleneck
// (doubling waves + halving per-wave MFMA:byte ratio grew stall cycles;
// all waves load IDENTICAL B addresses redundantly). Now each block stages
// the 4KB tile (hi 2KB | lo 2KB) ONCE via global_load_lds (width 16),
// double-buffered in LDS; 4 waves ds_read_b128 from it. The global etiles
// layout is pre-swizzled ([kb][code][8xu16] per tile) so the stage is
// lane*16-linear (global_load_lds requirement) AND the fragment read is
// base + lane*16 (2-way bank alias = free). Stage issued at iter top,
// __syncthreads drains vmcnt at iter end (~930 cyc MFMA cover >> L2 lat).
// esn register-prefetched one tile ahead (drained by same barrier).
// Geometry reverted to best-known R8: RF=4 (64 rows/wave), 512 blocks,
// 2 waves/SIMD. A-fragments PINNED one-time via empty asm ("+v").
//
// Top-2 gap < EPS_S flags rows into a global list; exact f64 re-solve.
// T=0 => z_out = z_q = e[best].

#define N_ROWS 131072
#define ZD 64
#define KCODES 2048
#define RF 4                 // 16-row fragments per wave (64 rows/wave)
#define EPS_S 2e-3f          // s-scale gap; realistic split error ~2e-5
#define FLAG_CAP 32768

using bf16x8  = __attribute__((ext_vector_type(8))) short;
using floatx4 = __attribute__((ext_vector_type(4))) float;

__device__ inline float bf2f(unsigned short u) {
    union { unsigned int i; float f; } c; c.i = ((unsigned int)u) << 16; return c.f;
}
__device__ inline unsigned short f2bf(float x) {
    union { float f; unsigned int i; } c; c.f = x;
    unsigned int b = c.i + 0x7FFFu + ((c.i >> 16) & 1u);
    return (unsigned short)(b >> 16);
}

// ws byte layout:
//       0: loss f32 | 4: flag count u32
//    4096: esn f32[2048]   (= -esq/2, summed in f64)
//   16384: esq64 f64[2048]
//   32768: etiles, 128 tiles x 4096B; tile = hi[kb][code][8] | lo[kb][code][8]
//          (u16; kb = dim>>3, code = c&15, j = dim&7)   ends 557056
//  557056: eT f32[64*2048]
// 1081344: flags u32[32768]   (ends 1212416)

__global__ void prep_kernel(const float* __restrict__ e, float* __restrict__ ws) {
    int t = threadIdx.x, lane = t & 63, w = t >> 6;
    if (blockIdx.x == 0 && t == 0) { ws[0] = 0.0f; ((unsigned int*)ws)[1] = 0u; }
    int c = blockIdx.x * 4 + w;                   // 512 blocks x 4 waves = 2048
    float* esn = ws + 1024;
    double* esq64 = (double*)((char*)ws + 16384);
    unsigned short* et = (unsigned short*)((char*)ws + 32768);
    float* eT = (float*)((char*)ws + 557056);

    float x = e[(size_t)c * ZD + lane];           // lane = dim k, coalesced
    unsigned short h = f2bf(x);
    unsigned short l = f2bf(x - bf2f(h));
    // swizzled tile layout: tile=c>>4 (2048 u16 stride), hi at +0, lo at +1024
    size_t base = ((size_t)(c >> 4) << 11) + ((lane >> 3) << 7) + ((c & 15) << 3) + (lane & 7);
    et[base]        = h;
    et[base + 1024] = l;
    eT[lane * KCODES + c] = x;
    double s = (double)x * (double)x;
    for (int off = 1; off < 64; off <<= 1) s += __shfl_xor(s, off, 64);
    if (lane == 0) { esq64[c] = s; esn[c] = (float)(-0.5 * s); }
}

// 24 MFMAs + argmax update for one 16-code tile.
// Two independent 3-chains per rf (acc: en-init, acc2: 0-init), summed.
// Top-2 invariant mval >= mv2: new mv2 = median(s, mval_old, mv2).
#define COMPUTE(H0, H1, L0, L1, EN, TT) do {                                 \
    float _fcol = (float)((TT) * 16 + lrow);                                 \
    floatx4 _ai = {EN, EN, EN, EN};                                          \
    floatx4 _zi = {0.0f, 0.0f, 0.0f, 0.0f};                                  \
    _Pragma("unroll")                                                        \
    for (int _rf = 0; _rf < RF; _rf++) {                                     \
        floatx4 acc  = _ai;                                                  \
        floatx4 acc2 = _zi;                                                  \
        acc  = __builtin_amdgcn_mfma_f32_16x16x32_bf16(Ah[_rf][0], H0, acc,  0, 0, 0); \
        acc2 = __builtin_amdgcn_mfma_f32_16x16x32_bf16(Ah[_rf][1], H1, acc2, 0, 0, 0); \
        acc  = __builtin_amdgcn_mfma_f32_16x16x32_bf16(Ah[_rf][0], L0, acc,  0, 0, 0); \
        acc2 = __builtin_amdgcn_mfma_f32_16x16x32_bf16(Ah[_rf][1], L1, acc2, 0, 0, 0); \
        acc  = __builtin_amdgcn_mfma_f32_16x16x32_bf16(Al[_rf][0], H0, acc,  0, 0, 0); \
        acc2 = __builtin_amdgcn_mfma_f32_16x16x32_bf16(Al[_rf][1], H1, acc2, 0, 0, 0); \
        _Pragma("unroll")                                                    \
        for (int _r = 0; _r < 4; _r++) {                                     \
            float _s  = acc[_r] + acc2[_r];                                  \
            bool  _gt = _s > mval[_rf][_r];                                  \
            mv2[_rf][_r]  = __builtin_amdgcn_fmed3f(_s, mval[_rf][_r], mv2[_rf][_r]); \
            midx[_rf][_r] = _gt ? _fcol : midx[_rf][_r];                     \
            mval[_rf][_r] = fmaxf(_s, mval[_rf][_r]);                        \
        }                                                                    \
    }                                                                        \
} while (0)

// Stage one 4KB tile into tilebuf[BUF]: 256 threads x 16B, lane*16-linear.
// LDS dest base is wave-uniform (w<<10); lane offset (lane*16) is implicit.
#define STAGE(BUF, TILE) do {                                                \
    const char* _src = (const char*)etiles + ((size_t)(TILE) << 12)          \
                       + ((size_t)threadIdx.x << 4);                         \
    __builtin_amdgcn_global_load_lds(                                        \
        (const __attribute__((address_space(1))) unsigned int*)_src,         \
        (__attribute__((address_space(3))) unsigned int*)&tilebuf[BUF][w << 10], \
        16, 0, 0);                                                           \
} while (0)

// One pipeline step: stage next tile, read+compute current from LDS, barrier.
#define ITER(BUF, CT) do {                                                   \
    int _nt = ((CT) + 1) & 127;                                              \
    STAGE((BUF) ^ 1, _nt);                                                   \
    float _nen = esn[_nt * 16 + lrow];                                       \
    bf16x8 h0 = *(const bf16x8*)(const void*)(tilebuf[BUF] + (lane << 4));   \
    bf16x8 h1 = *(const bf16x8*)(const void*)(tilebuf[BUF] + 1024 + (lane << 4)); \
    bf16x8 l0 = *(const bf16x8*)(const void*)(tilebuf[BUF] + 2048 + (lane << 4)); \
    bf16x8 l1 = *(const bf16x8*)(const void*)(tilebuf[BUF] + 3072 + (lane << 4)); \
    COMPUTE(h0, h1, l0, l1, cen, CT);                                        \
    __syncthreads();                                                         \
    cen = _nen;                                                              \
} while (0)

__global__ __launch_bounds__(256, 2) void vq_mfma(
        const float* __restrict__ z, const float* __restrict__ e,
        float* __restrict__ ws, float* __restrict__ out) {
    const float* esn = ws + 1024;
    const char* etiles = (const char*)ws + 32768;
    unsigned int* cntp  = (unsigned int*)ws + 1;
    unsigned int* flags = (unsigned int*)((char*)ws + 1081344);

    __shared__ __attribute__((aligned(16))) char tilebuf[2][4096];

    int lane = threadIdx.x & 63;
    int w    = threadIdx.x >> 6;
    int wid  = blockIdx.x * 4 + w;                // 0..2047
    int row0 = wid * (RF * 16);                   // 64 rows per wave
    int lrow = lane & 15;
    int lq   = lane >> 4;

    // Resident A fragments (hi+lo), A[m=lane&15][k=lq*8+j], kc = k-half
    bf16x8 Ah[RF][2], Al[RF][2];
#pragma unroll
    for (int rf = 0; rf < RF; rf++)
#pragma unroll
        for (int kc = 0; kc < 2; kc++) {
            const float* zp = z + (size_t)(row0 + rf * 16 + lrow) * ZD + kc * 32 + lq * 8;
            float xv[8];
            *(float4*)(void*)&xv[0] = *(const float4*)(const void*)zp;
            *(float4*)(void*)&xv[4] = *(const float4*)(const void*)(zp + 4);
            bf16x8 h, l;
#pragma unroll
            for (int j = 0; j < 8; j++) {
                unsigned short hb = f2bf(xv[j]);
                h[j] = (short)hb;
                l[j] = (short)f2bf(xv[j] - bf2f(hb));
            }
            Ah[rf][kc] = h; Al[rf][kc] = l;
            // Pin (ONE-TIME, outside loop): asm defs cannot be rematerialized
            // -> fragments stay register-resident across the 128-iter loop.
            asm volatile("" : "+v"(Ah[rf][kc]), "+v"(Al[rf][kc]));
        }

    // argmax state on s = dot - esq/2  (argmin d2 == argmax s)
    floatx4 mval[RF], mv2[RF], midx[RF];
#pragma unroll
    for (int rf = 0; rf < RF; rf++)
#pragma unroll
        for (int r = 0; r < 4; r++) {
            mval[rf][r] = -3.0e38f; mv2[rf][r] = -3.0e38f; midx[rf][r] = 0.0f;
        }

    // Pipeline prologue: stage tile 0, prefetch its esn, drain.
    STAGE(0, 0);
    float cen = esn[lrow];
    __syncthreads();

    for (int ct = 0; ct < 128; ct += 2) {
        ITER(0, ct);
        ITER(1, ct + 1);
    }

    float lacc = 0.0f;
#pragma unroll
    for (int rf = 0; rf < RF; rf++)
#pragma unroll
        for (int r = 0; r < 4; r++) {
            float v = mval[rf][r], v2 = mv2[rf][r], fi = midx[rf][r];
            // top-2 max-merge across the 16 lanes of this row (ties: smaller col)
            for (int off = 1; off < 16; off <<= 1) {
                float ov  = __shfl_xor(v,  off, 64);
                float ofi = __shfl_xor(fi, off, 64);
                float ov2 = __shfl_xor(v2, off, 64);
                bool take = (ov > v) || ((ov == v) && (ofi < fi));
                float loser = take ? v : ov;
                v2 = fmaxf(fmaxf(v2, ov2), loser);
                v  = take ? ov  : v;
                fi = take ? ofi : fi;
            }
            int row = row0 + rf * 16 + lq * 4 + r;
            int idx = (int)fi;
            float4 ev = ((const float4*)(const void*)(e + (size_t)idx * ZD))[lrow];
            float4 zv = ((const float4*)(const void*)(z + (size_t)row * ZD))[lrow];
            ((float4*)(void*)(out + (size_t)row * ZD))[lrow] = ev;
            float dx = ev.x - zv.x, dy = ev.y - zv.y;
            float dz = ev.z - zv.z, dw = ev.w - zv.w;
            lacc = fmaf(dx, dx, lacc); lacc = fmaf(dy, dy, lacc);
            lacc = fmaf(dz, dz, lacc); lacc = fmaf(dw, dw, lacc);
            if (lrow == 0) {
                out[(size_t)N_ROWS * ZD + row] = fi;
                if (v - v2 < EPS_S) {
                    unsigned int i = atomicAdd(cntp, 1u);
                    if (i < FLAG_CAP) flags[i] = (unsigned int)row;
                }
            }
        }

    for (int off = 1; off < 64; off <<= 1) lacc += __shfl_xor(lacc, off, 64);
    __shared__ float sm[4];
    if (lane == 0) sm[w] = lacc;
    __syncthreads();
    if (threadIdx.x == 0) atomicAdd(ws, sm[0] + sm[1] + sm[2] + sm[3]);
}

__global__ __launch_bounds__(256) void vq_fixup(
        const float* __restrict__ z, const float* __restrict__ e,
        float* __restrict__ ws, float* __restrict__ out) {
    const double* esq64 = (const double*)((const char*)ws + 16384);
    const float* eT = (const float*)((const char*)ws + 557056);
    const unsigned int* flags = (const unsigned int*)((const char*)ws + 1081344);
    unsigned int cnt = ((const unsigned int*)ws)[1];
    if (cnt > FLAG_CAP) cnt = FLAG_CAP;

    __shared__ float zrow[ZD];
    __shared__ double sd[4]; __shared__ int si[4]; __shared__ int sbest;
    int t = threadIdx.x, lane = t & 63, w = t >> 6;

    for (unsigned int u = blockIdx.x; u < cnt; u += gridDim.x) {
        int row = (int)flags[u];
        __syncthreads();                          // protect zrow from prev iter
        if (t < ZD) zrow[t] = z[(size_t)row * ZD + t];
        __syncthreads();

        double dacc[8];
#pragma unroll
        for (int j = 0; j < 8; j++) dacc[j] = 0.0;
        for (int k = 0; k < ZD; k++) {
            double zk = (double)zrow[k];
            const float* ek = eT + k * KCODES + t;
#pragma unroll
            for (int j = 0; j < 8; j++)
                dacc[j] = fma(zk, (double)ek[256 * j], dacc[j]);
        }
        double dmin = 1.0e300; int imin = 0;
#pragma unroll
        for (int j = 0; j < 8; j++) {             // ascending c: first wins
            int c = t + 256 * j;
            double d = fma(-2.0, dacc[j], esq64[c]);
            if (d < dmin) { dmin = d; imin = c; }
        }
        for (int off = 1; off < 64; off <<= 1) {
            double od = __shfl_xor(dmin, off, 64);
            int    oi = __shfl_xor(imin, off, 64);
            if (od < dmin || (od == dmin && oi < imin)) { dmin = od; imin = oi; }
        }
        if (lane == 0) { sd[w] = dmin; si[w] = imin; }
        __syncthreads();
        if (t == 0) {
            double bd = sd[0]; int bi = si[0];
            for (int q = 1; q < 4; q++)
                if (sd[q] < bd || (sd[q] == bd && si[q] < bi)) { bd = sd[q]; bi = si[q]; }
            sbest = bi;
        }
        __syncthreads();
        int bi = sbest;
        if (t < 16)
            ((float4*)(void*)(out + (size_t)row * ZD))[t] =
                ((const float4*)(const void*)(e + (size_t)bi * ZD))[t];
        if (t == 0) out[(size_t)N_ROWS * ZD + row] = (float)bi;
        // loss correction from flips: < EPS * ~700 / 8.4M < 2e-7 — ignored.
    }
}

__global__ void finalize_kernel(const float* __restrict__ ws,
                                float* __restrict__ out) {
    out[(size_t)N_ROWS * ZD + N_ROWS] = ws[0] * (1.0f / 8388608.0f);
}

extern "C" void kernel_launch(void* const* d_in, const int* in_sizes, int n_in,
                              void* d_out, int out_size, void* d_ws, size_t ws_size,
                              hipStream_t stream) {
    const float* z = (const float*)d_in[0];
    const float* e = (const float*)d_in[1];
    float* out = (float*)d_out;
    float* ws  = (float*)d_ws;

    prep_kernel<<<dim3(512), dim3(256), 0, stream>>>(e, ws);
    vq_mfma<<<dim3(512), dim3(256), 0, stream>>>(z, e, ws, out);
    vq_fixup<<<dim3(256), dim3(256), 0, stream>>>(z, e, ws, out);
    finalize_kernel<<<dim3(1), dim3(1), 0, stream>>>(ws, out);
}

// Round 4
// 196.644 us; speedup vs baseline: 1.7625x; 1.0081x over previous
//
#include <hip/hip_runtime.h>

// VQ quantizer, fp32: z [131072,64], e [2048,64].
// d_out (flat f32): z_q [131072*64] | indices [131072] (floats) | loss [1].
//
// 2-split bf16 MFMA scan (hh, hl, lh products), argmax of s = dot - esq/2.
//
// R10 (kept): LDS-staged B tiles via global_load_lds(16B), pre-swizzled
// global layout ([kb][code][8xu16] per 4KB tile) so staging is
// lane*16-linear and fragment reads are base+lane*16 (2-way alias, free).
// 157 -> 127us, MfmaUtil 27.7 -> 34.6.
//
// R11: amortize the barrier drain (m97-style structural stall: syncthreads
// = vmcnt(0)+lgkmcnt(0) full drain + rendezvous, paid 128x/wave):
//  - stage TWO 4KB tiles per iteration (8KB slab, double-buffered);
//    one __syncthreads per 32 codes instead of per 16 -> drain cost
//    amortized over ~1860 cyc of MFMA.
//  - esn staged to LDS once in prologue (8KB); per-tile read is a 4B
//    ds_read (broadcast across quads, conflict-free) instead of a
//    per-thread global load + addr calc.
//  - fcol maintained as float (+16.0/tile) instead of per-tile v_cvt.
//  - finalize folded into vq_fixup (stream-ordered after vq_mfma) -> 3
//    launches.
// Geometry: RF=4 (64 rows/wave), 512 blocks, 2 waves/SIMD.
// A-fragments PINNED one-time via empty asm ("+v") (anti-remat).
//
// Top-2 gap < EPS_S flags rows into a global list; exact f64 re-solve.
// T=0 => z_out = z_q = e[best].

#define N_ROWS 131072
#define ZD 64
#define KCODES 2048
#define RF 4                 // 16-row fragments per wave (64 rows/wave)
#define EPS_S 2e-3f          // s-scale gap; realistic split error ~2e-5
#define FLAG_CAP 32768

using bf16x8  = __attribute__((ext_vector_type(8))) short;
using floatx4 = __attribute__((ext_vector_type(4))) float;

__device__ inline float bf2f(unsigned short u) {
    union { unsigned int i; float f; } c; c.i = ((unsigned int)u) << 16; return c.f;
}
__device__ inline unsigned short f2bf(float x) {
    union { float f; unsigned int i; } c; c.f = x;
    unsigned int b = c.i + 0x7FFFu + ((c.i >> 16) & 1u);
    return (unsigned short)(b >> 16);
}

// ws byte layout:
//       0: loss f32 | 4: flag count u32
//    4096: esn f32[2048]   (= -esq/2, summed in f64)
//   16384: esq64 f64[2048]
//   32768: etiles, 128 tiles x 4096B; tile = hi[kb][code][8] | lo[kb][code][8]
//          (u16; kb = dim>>3, code = c&15, j = dim&7)   ends 557056
//  557056: eT f32[64*2048]
// 1081344: flags u32[32768]   (ends 1212416)

__global__ void prep_kernel(const float* __restrict__ e, float* __restrict__ ws) {
    int t = threadIdx.x, lane = t & 63, w = t >> 6;
    if (blockIdx.x == 0 && t == 0) { ws[0] = 0.0f; ((unsigned int*)ws)[1] = 0u; }
    int c = blockIdx.x * 4 + w;                   // 512 blocks x 4 waves = 2048
    float* esn = ws + 1024;
    double* esq64 = (double*)((char*)ws + 16384);
    unsigned short* et = (unsigned short*)((char*)ws + 32768);
    float* eT = (float*)((char*)ws + 557056);

    float x = e[(size_t)c * ZD + lane];           // lane = dim k, coalesced
    unsigned short h = f2bf(x);
    unsigned short l = f2bf(x - bf2f(h));
    // swizzled tile layout: tile=c>>4 (2048 u16 stride), hi at +0, lo at +1024
    size_t base = ((size_t)(c >> 4) << 11) + ((lane >> 3) << 7) + ((c & 15) << 3) + (lane & 7);
    et[base]        = h;
    et[base + 1024] = l;
    eT[lane * KCODES + c] = x;
    double s = (double)x * (double)x;
    for (int off = 1; off < 64; off <<= 1) s += __shfl_xor(s, off, 64);
    if (lane == 0) { esq64[c] = s; esn[c] = (float)(-0.5 * s); }
}

// 24 MFMAs + argmax update for one 16-code tile.
// Two independent 3-chains per rf (acc: en-init, acc2: 0-init), summed.
// Top-2 invariant mval >= mv2: new mv2 = median(s, mval_old, mv2).
#define COMPUTE(H0, H1, L0, L1, EN, FCOL) do {                               \
    floatx4 _ai = {EN, EN, EN, EN};                                          \
    floatx4 _zi = {0.0f, 0.0f, 0.0f, 0.0f};                                  \
    _Pragma("unroll")                                                        \
    for (int _rf = 0; _rf < RF; _rf++) {                                     \
        floatx4 acc  = _ai;                                                  \
        floatx4 acc2 = _zi;                                                  \
        acc  = __builtin_amdgcn_mfma_f32_16x16x32_bf16(Ah[_rf][0], H0, acc,  0, 0, 0); \
        acc2 = __builtin_amdgcn_mfma_f32_16x16x32_bf16(Ah[_rf][1], H1, acc2, 0, 0, 0); \
        acc  = __builtin_amdgcn_mfma_f32_16x16x32_bf16(Ah[_rf][0], L0, acc,  0, 0, 0); \
        acc2 = __builtin_amdgcn_mfma_f32_16x16x32_bf16(Ah[_rf][1], L1, acc2, 0, 0, 0); \
        acc  = __builtin_amdgcn_mfma_f32_16x16x32_bf16(Al[_rf][0], H0, acc,  0, 0, 0); \
        acc2 = __builtin_amdgcn_mfma_f32_16x16x32_bf16(Al[_rf][1], H1, acc2, 0, 0, 0); \
        _Pragma("unroll")                                                    \
        for (int _r = 0; _r < 4; _r++) {                                     \
            float _s  = acc[_r] + acc2[_r];                                  \
            bool  _gt = _s > mval[_rf][_r];                                  \
            mv2[_rf][_r]  = __builtin_amdgcn_fmed3f(_s, mval[_rf][_r], mv2[_rf][_r]); \
            midx[_rf][_r] = _gt ? (FCOL) : midx[_rf][_r];                    \
            mval[_rf][_r] = fmaxf(_s, mval[_rf][_r]);                        \
        }                                                                    \
    }                                                                        \
} while (0)

// Stage two consecutive 4KB tiles into tilebuf[BUF] (8KB slab).
// 256 threads x 16B per tile; LDS dest base is wave-uniform, lane*16 implicit.
#define STAGE2(BUF, TILE) do {                                               \
    const char* _s0 = etiles + ((size_t)((TILE) & 127) << 12)                \
                      + ((size_t)threadIdx.x << 4);                          \
    const char* _s1 = etiles + ((size_t)(((TILE) + 1) & 127) << 12)          \
                      + ((size_t)threadIdx.x << 4);                          \
    __builtin_amdgcn_global_load_lds(                                        \
        (const __attribute__((address_space(1))) unsigned int*)_s0,          \
        (__attribute__((address_space(3))) unsigned int*)&tilebuf[BUF][w << 10], \
        16, 0, 0);                                                           \
    __builtin_amdgcn_global_load_lds(                                        \
        (const __attribute__((address_space(1))) unsigned int*)_s1,          \
        (__attribute__((address_space(3))) unsigned int*)&tilebuf[BUF][4096 + (w << 10)], \
        16, 0, 0);                                                           \
} while (0)

// Read fragments for one 4KB tile at byte offset OFS within the slab.
#define READT(BUF, OFS, H0, H1, L0, L1) do {                                 \
    H0 = *(const bf16x8*)(const void*)(tilebuf[BUF] + (OFS) + (lane << 4));          \
    H1 = *(const bf16x8*)(const void*)(tilebuf[BUF] + (OFS) + 1024 + (lane << 4));   \
    L0 = *(const bf16x8*)(const void*)(tilebuf[BUF] + (OFS) + 2048 + (lane << 4));   \
    L1 = *(const bf16x8*)(const void*)(tilebuf[BUF] + (OFS) + 3072 + (lane << 4));   \
} while (0)

__global__ __launch_bounds__(256, 2) void vq_mfma(
        const float* __restrict__ z, const float* __restrict__ e,
        float* __restrict__ ws, float* __restrict__ out) {
    const char* etiles = (const char*)ws + 32768;
    unsigned int* cntp  = (unsigned int*)ws + 1;
    unsigned int* flags = (unsigned int*)((char*)ws + 1081344);

    __shared__ __attribute__((aligned(16))) char tilebuf[2][8192];
    __shared__ __attribute__((aligned(16))) float esn_sm[KCODES];

    int lane = threadIdx.x & 63;
    int w    = threadIdx.x >> 6;
    int wid  = blockIdx.x * 4 + w;                // 0..2047
    int row0 = wid * (RF * 16);                   // 64 rows per wave
    int lrow = lane & 15;
    int lq   = lane >> 4;

    // Prologue staging: esn (8KB, 2 calls) + tiles 0,1.
    {
        const char* esrc = (const char*)ws + 4096 + ((size_t)threadIdx.x << 4);
        __builtin_amdgcn_global_load_lds(
            (const __attribute__((address_space(1))) unsigned int*)esrc,
            (__attribute__((address_space(3))) unsigned int*)((char*)esn_sm + (w << 10)),
            16, 0, 0);
        __builtin_amdgcn_global_load_lds(
            (const __attribute__((address_space(1))) unsigned int*)(esrc + 4096),
            (__attribute__((address_space(3))) unsigned int*)((char*)esn_sm + 4096 + (w << 10)),
            16, 0, 0);
    }
    STAGE2(0, 0);

    // Resident A fragments (hi+lo), A[m=lane&15][k=lq*8+j], kc = k-half
    bf16x8 Ah[RF][2], Al[RF][2];
#pragma unroll
    for (int rf = 0; rf < RF; rf++)
#pragma unroll
        for (int kc = 0; kc < 2; kc++) {
            const float* zp = z + (size_t)(row0 + rf * 16 + lrow) * ZD + kc * 32 + lq * 8;
            float xv[8];
            *(float4*)(void*)&xv[0] = *(const float4*)(const void*)zp;
            *(float4*)(void*)&xv[4] = *(const float4*)(const void*)(zp + 4);
            bf16x8 h, l;
#pragma unroll
            for (int j = 0; j < 8; j++) {
                unsigned short hb = f2bf(xv[j]);
                h[j] = (short)hb;
                l[j] = (short)f2bf(xv[j] - bf2f(hb));
            }
            Ah[rf][kc] = h; Al[rf][kc] = l;
            // Pin (ONE-TIME, outside loop): asm defs cannot be rematerialized
            // -> fragments stay register-resident across the 64-iter loop.
            asm volatile("" : "+v"(Ah[rf][kc]), "+v"(Al[rf][kc]));
        }

    // argmax state on s = dot - esq/2  (argmin d2 == argmax s)
    floatx4 mval[RF], mv2[RF], midx[RF];
#pragma unroll
    for (int rf = 0; rf < RF; rf++)
#pragma unroll
        for (int r = 0; r < 4; r++) {
            mval[rf][r] = -3.0e38f; mv2[rf][r] = -3.0e38f; midx[rf][r] = 0.0f;
        }

    float fcol = (float)lrow;                     // maintained: +16 per tile
    __syncthreads();                              // drain prologue stages

    for (int ct = 0; ct < 128; ct += 4) {
        // slab 0: tiles ct, ct+1 ; stage tiles ct+2, ct+3 into slab 1
        STAGE2(1, ct + 2);
        {
            float en0 = esn_sm[ct * 16 + lrow];
            float en1 = esn_sm[ct * 16 + 16 + lrow];
            bf16x8 h0, h1, l0, l1;
            READT(0, 0, h0, h1, l0, l1);
            COMPUTE(h0, h1, l0, l1, en0, fcol);
            fcol += 16.0f;
            READT(0, 4096, h0, h1, l0, l1);
            COMPUTE(h0, h1, l0, l1, en1, fcol);
            fcol += 16.0f;
        }
        __syncthreads();
        // slab 1: tiles ct+2, ct+3 ; stage tiles ct+4, ct+5 into slab 0
        STAGE2(0, ct + 4);                        // wraps on last iter; harmless
        {
            float en0 = esn_sm[ct * 16 + 32 + lrow];
            float en1 = esn_sm[ct * 16 + 48 + lrow];
            bf16x8 h0, h1, l0, l1;
            READT(1, 0, h0, h1, l0, l1);
            COMPUTE(h0, h1, l0, l1, en0, fcol);
            fcol += 16.0f;
            READT(1, 4096, h0, h1, l0, l1);
            COMPUTE(h0, h1, l0, l1, en1, fcol);
            fcol += 16.0f;
        }
        __syncthreads();
    }

    float lacc = 0.0f;
#pragma unroll
    for (int rf = 0; rf < RF; rf++)
#pragma unroll
        for (int r = 0; r < 4; r++) {
            float v = mval[rf][r], v2 = mv2[rf][r], fi = midx[rf][r];
            // top-2 max-merge across the 16 lanes of this row (ties: smaller col)
            for (int off = 1; off < 16; off <<= 1) {
                float ov  = __shfl_xor(v,  off, 64);
                float ofi = __shfl_xor(fi, off, 64);
                float ov2 = __shfl_xor(v2, off, 64);
                bool take = (ov > v) || ((ov == v) && (ofi < fi));
                float loser = take ? v : ov;
                v2 = fmaxf(fmaxf(v2, ov2), loser);
                v  = take ? ov  : v;
                fi = take ? ofi : fi;
            }
            int row = row0 + rf * 16 + lq * 4 + r;
            int idx = (int)fi;
            float4 ev = ((const float4*)(const void*)(e + (size_t)idx * ZD))[lrow];
            float4 zv = ((const float4*)(const void*)(z + (size_t)row * ZD))[lrow];
            ((float4*)(void*)(out + (size_t)row * ZD))[lrow] = ev;
            float dx = ev.x - zv.x, dy = ev.y - zv.y;
            float dz = ev.z - zv.z, dw = ev.w - zv.w;
            lacc = fmaf(dx, dx, lacc); lacc = fmaf(dy, dy, lacc);
            lacc = fmaf(dz, dz, lacc); lacc = fmaf(dw, dw, lacc);
            if (lrow == 0) {
                out[(size_t)N_ROWS * ZD + row] = fi;
                if (v - v2 < EPS_S) {
                    unsigned int i = atomicAdd(cntp, 1u);
                    if (i < FLAG_CAP) flags[i] = (unsigned int)row;
                }
            }
        }

    for (int off = 1; off < 64; off <<= 1) lacc += __shfl_xor(lacc, off, 64);
    __shared__ float sm[4];
    if (lane == 0) sm[w] = lacc;
    __syncthreads();
    if (threadIdx.x == 0) atomicAdd(ws, sm[0] + sm[1] + sm[2] + sm[3]);
}

__global__ __launch_bounds__(256) void vq_fixup(
        const float* __restrict__ z, const float* __restrict__ e,
        float* __restrict__ ws, float* __restrict__ out) {
    const double* esq64 = (const double*)((const char*)ws + 16384);
    const float* eT = (const float*)((const char*)ws + 557056);
    const unsigned int* flags = (const unsigned int*)((const char*)ws + 1081344);
    unsigned int cnt = ((const unsigned int*)ws)[1];
    if (cnt > FLAG_CAP) cnt = FLAG_CAP;

    // finalize folded in: stream-ordered after vq_mfma, ws[0] is final.
    if (blockIdx.x == 0 && threadIdx.x == 0)
        out[(size_t)N_ROWS * ZD + N_ROWS] = ws[0] * (1.0f / 8388608.0f);

    __shared__ float zrow[ZD];
    __shared__ double sd[4]; __shared__ int si[4]; __shared__ int sbest;
    int t = threadIdx.x, lane = t & 63, w = t >> 6;

    for (unsigned int u = blockIdx.x; u < cnt; u += gridDim.x) {
        int row = (int)flags[u];
        __syncthreads();                          // protect zrow from prev iter
        if (t < ZD) zrow[t] = z[(size_t)row * ZD + t];
        __syncthreads();

        double dacc[8];
#pragma unroll
        for (int j = 0; j < 8; j++) dacc[j] = 0.0;
        for (int k = 0; k < ZD; k++) {
            double zk = (double)zrow[k];
            const float* ek = eT + k * KCODES + t;
#pragma unroll
            for (int j = 0; j < 8; j++)
                dacc[j] = fma(zk, (double)ek[256 * j], dacc[j]);
        }
        double dmin = 1.0e300; int imin = 0;
#pragma unroll
        for (int j = 0; j < 8; j++) {             // ascending c: first wins
            int c = t + 256 * j;
            double d = fma(-2.0, dacc[j], esq64[c]);
            if (d < dmin) { dmin = d; imin = c; }
        }
        for (int off = 1; off < 64; off <<= 1) {
            double od = __shfl_xor(dmin, off, 64);
            int    oi = __shfl_xor(imin, off, 64);
            if (od < dmin || (od == dmin && oi < imin)) { dmin = od; imin = oi; }
        }
        if (lane == 0) { sd[w] = dmin; si[w] = imin; }
        __syncthreads();
        if (t == 0) {
            double bd = sd[0]; int bi = si[0];
            for (int q = 1; q < 4; q++)
                if (sd[q] < bd || (sd[q] == bd && si[q] < bi)) { bd = sd[q]; bi = si[q]; }
            sbest = bi;
        }
        __syncthreads();
        int bi = sbest;
        if (t < 16)
            ((float4*)(void*)(out + (size_t)row * ZD))[t] =
                ((const float4*)(const void*)(e + (size_t)bi * ZD))[t];
        if (t == 0) out[(size_t)N_ROWS * ZD + row] = (float)bi;
        // loss correction from flips: < EPS * ~700 / 8.4M < 2e-7 — ignored.
    }
}

extern "C" void kernel_launch(void* const* d_in, const int* in_sizes, int n_in,
                              void* d_out, int out_size, void* d_ws, size_t ws_size,
                              hipStream_t stream) {
    const float* z = (const float*)d_in[0];
    const float* e = (const float*)d_in[1];
    float* out = (float*)d_out;
    float* ws  = (float*)d_ws;

    prep_kernel<<<dim3(512), dim3(256), 0, stream>>>(e, ws);
    vq_mfma<<<dim3(512), dim3(256), 0, stream>>>(z, e, ws, out);
    vq_fixup<<<dim3(256), dim3(256), 0, stream>>>(z, e, ws, out);
}